// Round 5
// baseline (265.059 us; speedup 1.0000x reference)
//
#include <hip/hip_runtime.h>
#include <math.h>

#define EPS 1e-5f

typedef _Float16 half4 __attribute__((ext_vector_type(4)));
typedef _Float16 half8 __attribute__((ext_vector_type(8)));
typedef float floatx4 __attribute__((ext_vector_type(4)));

// ---------------------------------------------------------------------------
// K0: x (N,C,H,W) fp32 -> xt2[b=(n,w)][i=h][c] fp16.
// Per (n,h): transpose 128x128 (c,w) -> (w,c). grid=(1024, 2, 2), block=256.
// ---------------------------------------------------------------------------
__global__ void transpose_cvt_k(const float* __restrict__ x, _Float16* __restrict__ xt2) {
  __shared__ float tile[64][65];
  int nh = blockIdx.x;
  int n = nh >> 7, h = nh & 127;
  int c0 = blockIdx.y * 64, w0 = blockIdx.z * 64;
  const float* src = x + (size_t)n * 2097152 + (size_t)h * 128;  // (c,w)
  _Float16* dst = xt2 + (size_t)n * 2097152 + (size_t)h * 128;   // (w,c)
  int lane = threadIdx.x & 63;
  int tr = threadIdx.x >> 6;
#pragma unroll
  for (int rr = tr; rr < 64; rr += 4)
    tile[rr][lane] = src[(size_t)(c0 + rr) * 16384 + w0 + lane];
  __syncthreads();
#pragma unroll
  for (int cc = tr; cc < 64; cc += 4)
    dst[(size_t)(w0 + cc) * 16384 + c0 + lane] = (_Float16)tile[lane][cc];
}

// ---------------------------------------------------------------------------
// K_F: fused qkv-GEMM + MFMA attention. One wave per (b, quarter).
// grid = 4096 = qtr*1024 + b  (qtr-major so the 4 siblings of b share an XCD).
// Phase 1: wave computes its 64-ch qkv slab = BN(W[ch][c] @ xt2[b][h][c]^T)
//   via 16x16x32 f16 MFMA (4 mt x 8 nt x 4 k-steps), writes fp16 into
//   qkvlds[h][ch_local] (stride 72 halves; b64 writes, 2-way bank alias=free).
// Phase 2: round-4 attention for the wave's 2 groups, fragments from LDS:
//   kf/qf = single ds_read_b128 each (channels contiguous!), vf scalar.
//   No __syncthreads anywhere: each wave produces exactly what it consumes.
// ---------------------------------------------------------------------------
__global__ void __launch_bounds__(64, 2) fused_qkv_attn(
    const _Float16* __restrict__ xt2, const float* __restrict__ wq,
    const float* __restrict__ qg, const float* __restrict__ qb,
    const float* __restrict__ qm, const float* __restrict__ qv,
    const float* __restrict__ sg, const float* __restrict__ sb,
    const float* __restrict__ sm, const float* __restrict__ svv,
    const float* __restrict__ og, const float* __restrict__ ob,
    const float* __restrict__ om, const float* __restrict__ ov,
    _Float16* __restrict__ svout) {
  __shared__ _Float16 qkvlds[128 * 72];  // [h][ch_local 64 + pad 8]
  __shared__ _Float16 plds[16 * 136];    // P round-trip, round-4 layout
  int bq = blockIdx.x;
  int b = bq & 1023;
  int qtr = bq >> 10;
  int t = threadIdx.x;  // 0..63
  int n = t & 15;
  int q4 = t >> 4;

  const _Float16* xb = xt2 + (size_t)b * 16384;

  // ---- Phase 1: GEMM. acc[mt][nt]: ch = qtr*64+mt*16+q4*4+r, h = nt*16+n.
  floatx4 acc[4][8];
#pragma unroll
  for (int mt = 0; mt < 4; mt++)
#pragma unroll
    for (int nt = 0; nt < 8; nt++)
#pragma unroll
      for (int r = 0; r < 4; r++) acc[mt][nt][r] = 0.f;

#pragma unroll
  for (int k0 = 0; k0 < 128; k0 += 32) {
    half8 af[4];
#pragma unroll
    for (int mt = 0; mt < 4; mt++) {
      const float* wp = wq + (size_t)(qtr * 64 + mt * 16 + n) * 128 + k0 + q4 * 8;
      float4 a0 = *(const float4*)wp;
      float4 a1 = *(const float4*)(wp + 4);
      half8 h;
      h[0] = (_Float16)a0.x; h[1] = (_Float16)a0.y; h[2] = (_Float16)a0.z; h[3] = (_Float16)a0.w;
      h[4] = (_Float16)a1.x; h[5] = (_Float16)a1.y; h[6] = (_Float16)a1.z; h[7] = (_Float16)a1.w;
      af[mt] = h;
    }
    half8 bf[8];
#pragma unroll
    for (int nt = 0; nt < 8; nt++)
      bf[nt] = *(const half8*)(xb + (size_t)(nt * 16 + n) * 128 + k0 + q4 * 8);
#pragma unroll
    for (int mt = 0; mt < 4; mt++)
#pragma unroll
      for (int nt = 0; nt < 8; nt++)
        acc[mt][nt] = __builtin_amdgcn_mfma_f32_16x16x32_f16(af[mt], bf[nt], acc[mt][nt], 0, 0, 0);
  }

  // qkv-BN coeffs for this lane's 16 (mt,r) channel rows
  float qsc[4][4], qbi[4][4];
#pragma unroll
  for (int mt = 0; mt < 4; mt++)
#pragma unroll
    for (int r = 0; r < 4; r++) {
      int o = qtr * 64 + mt * 16 + q4 * 4 + r;
      float sc = qg[o] * rsqrtf(qv[o] + EPS);
      qsc[mt][r] = sc;
      qbi[mt][r] = qb[o] - qm[o] * sc;
    }

  // epilogue: BN + fp16, write qkvlds[h][ch_local] (4 consecutive ch per b64)
#pragma unroll
  for (int mt = 0; mt < 4; mt++)
#pragma unroll
    for (int nt = 0; nt < 8; nt++) {
      int h = nt * 16 + n;
      half4 hh;
#pragma unroll
      for (int r = 0; r < 4; r++)
        hh[r] = (_Float16)fmaf(acc[mt][nt][r], qsc[mt][r], qbi[mt][r]);
      *(half4*)(&qkvlds[h * 72 + mt * 16 + q4 * 4]) = hh;
    }

  // ---- Phase 2: attention for the wave's two groups
#pragma unroll 1
  for (int gl = 0; gl < 2; gl++) {
    int g = qtr * 2 + gl;
    int chb = gl * 32;

    // k fragments: A[m=j][k=ch replicated per quad] — one b128 per j-tile
    half8 kf[8];
#pragma unroll
    for (int jt = 0; jt < 8; jt++)
      kf[jt] = *(const half8*)(&qkvlds[(jt * 16 + n) * 72 + chb + 8]);

    // v fragments: A[m=c][k=j]: scalar gathers from qkvlds[j][chb+16+c]
    half8 vf[4];
#pragma unroll
    for (int ks = 0; ks < 4; ks++)
#pragma unroll
      for (int jj = 0; jj < 8; jj++)
        vf[ks][jj] = qkvlds[(ks * 32 + q4 * 8 + jj) * 72 + chb + 16 + n];

    float s_scale = sg[g] * rsqrtf(svv[g] + EPS);
    float sc4 = s_scale * 0.25f;  // /4 for quad replication
    float s_bias = sb[g] - sm[g] * s_scale;

    float osc[4], obi[4];
#pragma unroll
    for (int r = 0; r < 4; r++) {
      int oc = g * 16 + q4 * 4 + r;
      float s0 = og[oc] * rsqrtf(ov[oc] + EPS);
      osc[r] = s0;
      obi[r] = ob[oc] - om[oc] * s0;
    }

    for (int st8 = 0; st8 < 8; st8++) {
      // q fragment (B-operand): one b128
      half8 qf = *(const half8*)(&qkvlds[(st8 * 16 + n) * 72 + chb]);

      floatx4 stt[8];
#pragma unroll
      for (int jt = 0; jt < 8; jt++) {
        floatx4 z = {0.f, 0.f, 0.f, 0.f};
        stt[jt] = __builtin_amdgcn_mfma_f32_16x16x32_f16(kf[jt], qf, z, 0, 0, 0);
      }

      float mx = -1e30f;
#pragma unroll
      for (int jt = 0; jt < 8; jt++)
#pragma unroll
        for (int r = 0; r < 4; r++) {
          stt[jt][r] = fmaf(stt[jt][r], sc4, s_bias);
          mx = fmaxf(mx, stt[jt][r]);
        }
      mx = fmaxf(mx, __shfl_xor(mx, 16));
      mx = fmaxf(mx, __shfl_xor(mx, 32));

      float ls = 0.f;
#pragma unroll
      for (int jt = 0; jt < 8; jt++)
#pragma unroll
        for (int r = 0; r < 4; r++) {
          float e = __expf(stt[jt][r] - mx);
          stt[jt][r] = e;
          ls += e;
        }
      ls += __shfl_xor(ls, 16);
      ls += __shfl_xor(ls, 32);

      // P -> LDS fp16 (lane holds 4 consecutive j)
#pragma unroll
      for (int jt = 0; jt < 8; jt++) {
        half4 h;
        h[0] = (_Float16)stt[jt][0];
        h[1] = (_Float16)stt[jt][1];
        h[2] = (_Float16)stt[jt][2];
        h[3] = (_Float16)stt[jt][3];
        *(half4*)(&plds[n * 136 + jt * 16 + q4 * 4]) = h;
      }

      // PV: O[c][i] accumulate over K=128 j
      floatx4 oacc = {0.f, 0.f, 0.f, 0.f};
#pragma unroll
      for (int ks = 0; ks < 4; ks++) {
        half8 pf = *(const half8*)(&plds[n * 136 + ks * 32 + q4 * 8]);
        oacc = __builtin_amdgcn_mfma_f32_16x16x32_f16(vf[ks], pf, oacc, 0, 0, 0);
      }

      float invl = 1.f / ls;
      _Float16* outp = svout + ((size_t)b * 128 + g * 16 + q4 * 4) * 128 + st8 * 16 + n;
#pragma unroll
      for (int r = 0; r < 4; r++)
        outp[(size_t)r * 128] = (_Float16)fmaf(oacc[r] * invl, osc[r], obi[r]);
    }
  }
}

// ---------------------------------------------------------------------------
// K3: tiled transpose fp16 -> fp32: in (B, R, C) -> out (B, C, R).
// ---------------------------------------------------------------------------
__global__ void transpose_h2f_k(const _Float16* __restrict__ in, float* __restrict__ out,
                                int R, int C) {
  __shared__ float tile[64][65];
  int nblk = blockIdx.x;
  int r0 = blockIdx.y * 64;
  int c0 = blockIdx.z * 64;
  const _Float16* src = in + (size_t)nblk * R * C;
  float* dst = out + (size_t)nblk * R * C;
  int lane = threadIdx.x & 63;
  int tr = threadIdx.x >> 6;
#pragma unroll
  for (int rr = tr; rr < 64; rr += 4)
    tile[rr][lane] = (float)src[(size_t)(r0 + rr) * C + c0 + lane];
  __syncthreads();
#pragma unroll
  for (int cc = tr; cc < 64; cc += 4)
    dst[(size_t)(c0 + cc) * R + r0 + lane] = tile[lane][cc];
}

// ---------------------------------------------------------------------------
extern "C" void kernel_launch(void* const* d_in, const int* in_sizes, int n_in,
                              void* d_out, int out_size, void* d_ws, size_t ws_size,
                              hipStream_t stream) {
  const float* x  = (const float*)d_in[0];
  const float* wq = (const float*)d_in[1];
  const float* qg = (const float*)d_in[2];
  const float* qb = (const float*)d_in[3];
  const float* qm = (const float*)d_in[4];
  const float* qv = (const float*)d_in[5];
  const float* sg = (const float*)d_in[6];
  const float* sb = (const float*)d_in[7];
  const float* sm = (const float*)d_in[8];
  const float* sv = (const float*)d_in[9];
  const float* og = (const float*)d_in[10];
  const float* ob = (const float*)d_in[11];
  const float* om = (const float*)d_in[12];
  const float* ov = (const float*)d_in[13];
  float* out = (float*)d_out;

  // workspace: xt2 32MB | svh 32MB
  _Float16* xt2 = (_Float16*)d_ws;
  _Float16* svh = xt2 + (size_t)1024 * 128 * 128;

  // K0: x -> xt2[b][i][c] fp16
  transpose_cvt_k<<<dim3(1024, 2, 2), 256, 0, stream>>>(x, xt2);
  // K_F: fused qkv GEMM + attention -> svh fp16
  fused_qkv_attn<<<4096, 64, 0, stream>>>(xt2, wq, qg, qb, qm, qv,
                                          sg, sb, sm, sv, og, ob, om, ov, svh);
  // K3: svh (8, 128w, 16384oi) fp16 -> out (8, 16384, 128w) fp32 = (N,O,H,W)
  transpose_h2f_k<<<dim3(8, 2, 256), 256, 0, stream>>>(svh, out, 128, 16384);
}